// Round 9
// baseline (372.637 us; speedup 1.0000x reference)
//
#include <hip/hip_runtime.h>
#include <hip/hip_bf16.h>

// B=4, S=2048, D=1024, H=16, HD=64.
// Input dtype detected inline (fp32 vs bf16); compute pipeline is bf16 MFMA.
#define B_  4
#define S_  2048
#define D_  1024
#define H_  16
#define HD_ 64

using short4_ = __attribute__((ext_vector_type(4))) short;
using short8  = __attribute__((ext_vector_type(8))) short;
using floatx4 = __attribute__((ext_vector_type(4))) float;

#define MFMA16(a, b, c) __builtin_amdgcn_mfma_f32_16x16x32_bf16((a), (b), (c), 0, 0, 0)

// softmax scale folded into Q at QKV-GEMM epilogue: (1/sqrt(64)) * log2(e)
#define QSCALE (0.125f * 1.4426950408889634f)

static __device__ __forceinline__ short f_to_bf16(float f) {
    __hip_bfloat16 h = __float2bfloat16(f);
    short s;
    __builtin_memcpy(&s, &h, 2);
    return s;
}

// async global->LDS, 16B per lane; LDS dst must be wave-uniform base + lane*16.
static __device__ __forceinline__ void gl_lds16(const short* g, short* l) {
    __builtin_amdgcn_global_load_lds(
        (const __attribute__((address_space(1))) void*)g,
        (__attribute__((address_space(3))) void*)l, 16, 0, 0);
}

// Inline dtype detect: lanes 0..63 read x's first 64 dwords as fp32.
static __device__ __forceinline__ bool detect_fp32(const unsigned int* __restrict__ xraw) {
    const float f = __uint_as_float(xraw[threadIdx.x & 63]);
    const bool weird = !(f == f) || fabsf(f) > 1e30f;
    return __ballot(weird) == 0ull;
}

// ---------------------------------------------------------------------------
// Merged convert: virtual concat [x | Wq | Wk | Wv | Wo] -> contiguous
// bf16 [xb | wqkv(3) | wob]. One launch.
// ---------------------------------------------------------------------------
__global__ __launch_bounds__(256) void convert_all_kernel(
    const void* __restrict__ x,  const void* __restrict__ wq,
    const void* __restrict__ wk, const void* __restrict__ wv,
    const void* __restrict__ wo, short* __restrict__ dst,
    const unsigned int* __restrict__ xraw)
{
    const bool isf32 = detect_fp32(xraw);
    const size_t NE = (size_t)B_ * S_ * D_;   // 8388608
    const size_t NW = (size_t)D_ * D_;        // 1048576 = 2^20
    const size_t i = ((size_t)blockIdx.x * 256 + threadIdx.x) * 8;

    const void* src;
    size_t off;
    if (i < NE) { src = x; off = i; }
    else {
        const size_t j = i - NE;
        const int r = (int)(j >> 20);
        src = (r == 0) ? wq : (r == 1) ? wk : (r == 2) ? wv : wo;
        off = j & (NW - 1);
    }

    if (isf32) {
        const float* s = (const float*)src + off;
        short8 o;
#pragma unroll
        for (int j2 = 0; j2 < 8; ++j2) o[j2] = f_to_bf16(s[j2]);
        *(short8*)(dst + i) = o;
    } else {
        *(short8*)(dst + i) = *(const short8*)((const short*)src + off);
    }
}

// ---------------------------------------------------------------------------
// 256x128-tile pipelined GEMM core, shared by qkv and xwT kernels.
// (unchanged -- verified working, rounds 4-8)
// ---------------------------------------------------------------------------
#define STAGE6(BUF, KO)                                                         \
  { const short* a0_ = gA + (KO);                                               \
    gl_lds16(a0_,            (BUF) +     0 + tid * 8);                          \
    gl_lds16(a0_ +  64 * D_, (BUF) +  4096 + tid * 8);                          \
    gl_lds16(a0_ + 128 * D_, (BUF) +  8192 + tid * 8);                          \
    gl_lds16(a0_ + 192 * D_, (BUF) + 12288 + tid * 8);                          \
    const short* b0_ = gB + (KO);                                               \
    gl_lds16(b0_,            (BUF) + 16384 + tid * 8);                          \
    gl_lds16(b0_ +  64 * D_, (BUF) + 20480 + tid * 8); }

#define READ_FRAGS(AF, BF, BUF)                                                 \
  { _Pragma("unroll")                                                           \
    for (int mi = 0; mi < 4; ++mi) {                                            \
      AF[mi][0] = *(const short8*)&(BUF)[(wm + 16*mi + l15) * 64 + ((    quad + l15) & 7) * 8]; \
      AF[mi][1] = *(const short8*)&(BUF)[(wm + 16*mi + l15) * 64 + ((4 + quad + l15) & 7) * 8]; \
    }                                                                           \
    _Pragma("unroll")                                                           \
    for (int ni = 0; ni < 4; ++ni) {                                            \
      BF[ni][0] = *(const short8*)&(BUF)[16384 + (wn + 16*ni + l15) * 64 + ((    quad + l15) & 7) * 8]; \
      BF[ni][1] = *(const short8*)&(BUF)[16384 + (wn + 16*ni + l15) * 64 + ((4 + quad + l15) & 7) * 8]; \
    } }

#define DO_MFMA(AF, BF)                                                         \
  { __builtin_amdgcn_s_setprio(1);                                              \
    _Pragma("unroll")                                                           \
    for (int mi = 0; mi < 4; ++mi)                                              \
      _Pragma("unroll")                                                         \
      for (int ni = 0; ni < 4; ++ni) {                                          \
        acc[mi][ni] = MFMA16(AF[mi][0], BF[ni][0], acc[mi][ni]);                \
        acc[mi][ni] = MFMA16(AF[mi][1], BF[ni][1], acc[mi][ni]);                \
      }                                                                         \
    __builtin_amdgcn_s_setprio(0); }

#define GEMM_BODY(CURB, NXTB, AF_U, BF_U, AF_F, BF_F, KO2, S1, S2)              \
  {                                                                             \
    asm volatile("s_waitcnt lgkmcnt(0)" ::: "memory");                          \
    __builtin_amdgcn_s_barrier();                                               \
    if (S2) STAGE6(CURB, KO2)                                                   \
    if (S2) { asm volatile("s_waitcnt vmcnt(6)" ::: "memory"); }                \
    else    { asm volatile("s_waitcnt vmcnt(0)" ::: "memory"); }                \
    __builtin_amdgcn_s_barrier();                                               \
    if (S1) READ_FRAGS(AF_F, BF_F, NXTB)                                        \
    DO_MFMA(AF_U, BF_U)                                                         \
  }

#define GEMM_PREAMBLE                                                           \
    const int tid  = threadIdx.x;                                               \
    const int wave = tid >> 6;                                                  \
    const int lane = tid & 63;                                                  \
    const int quad = lane >> 4;                                                 \
    const int l15  = lane & 15;                                                 \
    const int wm   = (wave >> 1) * 64;                                          \
    const int wn   = (wave & 1) * 64;                                           \
    const int rS   = tid >> 3;                                                  \
    const int sb8  = (((tid & 7) - rS) & 7) * 8;                                \
    short* const buf0 = Lds;                                                    \
    short* const buf1 = Lds + 24576;                                            \
    short8 afA[4][2], bfA[4][2], afB[4][2], bfB[4][2];                          \
    floatx4 acc[4][4] = {};

#define GEMM_KLOOP                                                              \
    STAGE6(buf0, 0)                                                             \
    STAGE6(buf1, 64)                                                            \
    asm volatile("s_waitcnt vmcnt(6)" ::: "memory");                            \
    __builtin_amdgcn_s_barrier();                                               \
    READ_FRAGS(afA, bfA, buf0)                                                  \
    int ko = 128;                                                               \
    for (int it = 0; it < 7; ++it) {                                            \
        GEMM_BODY(buf0, buf1, afA, bfA, afB, bfB, ko,      true, true)          \
        GEMM_BODY(buf1, buf0, afB, bfB, afA, bfA, ko + 64, true, true)          \
        ko += 128;                                                               \
    }                                                                           \
    GEMM_BODY(buf0, buf1, afA, bfA, afB, bfB, 0, true,  false)  /* t=14 */      \
    GEMM_BODY(buf1, buf0, afB, bfB, afA, bfA, 0, false, false)  /* t=15 */

// ---------------------------------------------------------------------------
// Fused QKV GEMM. W = concat(Wq,Wk,Wv) rows [3072][1024]. Grid 32 x 24 =
// 768 blocks = exactly 3 full rounds on 256 CUs (zero tail waste).
// ---------------------------------------------------------------------------
__global__ __launch_bounds__(512, 2) void gemm_qkv256_kernel(
    const short* __restrict__ X, const short* __restrict__ W,
    short* __restrict__ Yq, short* __restrict__ Yk, short* __restrict__ VT)
{
    __shared__ __align__(16) short Lds[49152];   // 96 KiB

    GEMM_PREAMBLE

    const int mBase = blockIdx.x * 256;
    const int nTot  = blockIdx.y * 128;          // 0..2943
    const int sel   = nTot >> 10;                // 0=q,1=k,2=v
    const int nBase = nTot & 1023;

    const short* gA = X + (size_t)(mBase + rS) * D_ + sb8;
    const short* gB = W + (size_t)(nTot  + rS) * D_ + sb8;

    GEMM_KLOOP

    if (sel < 2) {
        short* Y = (sel == 0) ? Yq : Yk;
        const float osc = (sel == 0) ? QSCALE : 1.0f;
#pragma unroll
        for (int mi = 0; mi < 4; ++mi)
#pragma unroll
        for (int ni = 0; ni < 4; ++ni)
#pragma unroll
        for (int r = 0; r < 4; ++r) {
            const size_t idx =
                (size_t)(mBase + wm + 16 * mi + 4 * quad + r) * D_ +
                (nBase + wn + 16 * ni + l15);
            Y[idx] = f_to_bf16(acc[mi][ni][r] * osc);
        }
    } else {
        // V^T epilogue: LDS transpose (Tb = 128 chans x 256 m, stride 264),
        // coalesced 512B-row writes to VT.
        const int bb = mBase >> 11;     // batch
        const int s0 = mBase & 2047;    // seq base
        short* Tb = Lds;
        __syncthreads();   // k-loop fully drained; LDS free
#pragma unroll
        for (int ni = 0; ni < 4; ++ni)
#pragma unroll
        for (int mi = 0; mi < 4; ++mi) {
            short4_ v4;
#pragma unroll
            for (int r = 0; r < 4; ++r) v4[r] = f_to_bf16(acc[mi][ni][r]);
            *(short4_*)&Tb[(wn + 16 * ni + l15) * 264 + wm + 16 * mi + 4 * quad] = v4;
        }
        __syncthreads();
#pragma unroll
        for (int p = 0; p < 8; ++p) {
            const int t2 = tid + p * 512;
            const int cl = t2 >> 5;           // 0..127
            const int mc = (t2 & 31) * 8;     // 0..248
            const short8 val = *(const short8*)&Tb[cl * 264 + mc];
            const int c  = nBase + cl;        // global channel
            const int hh = c >> 6, hd = c & 63;
            *(short8*)&VT[((size_t)(bb * H_ + hh) * HD_ + hd) * S_ + s0 + mc] = val;
        }
    }
}

// ---------------------------------------------------------------------------
// Wo projection: Y = ctx @ Wo^T. Grid 32 x 8 = 256 blocks = exactly 1 round.
// ---------------------------------------------------------------------------
__global__ __launch_bounds__(512, 2) void gemm_xwT_kernel(
    const short* __restrict__ X, const short* __restrict__ W,
    void* __restrict__ Y, const unsigned int* __restrict__ xraw)
{
    __shared__ __align__(16) short Lds[49152];   // 96 KiB

    const bool f32out = detect_fp32(xraw);

    GEMM_PREAMBLE

    const int mBase = blockIdx.x * 256;
    const int nBase = blockIdx.y * 128;

    const short* gA = X + (size_t)(mBase + rS) * D_ + sb8;
    const short* gB = W + (size_t)(nBase + rS) * D_ + sb8;

    GEMM_KLOOP

#pragma unroll
    for (int mi = 0; mi < 4; ++mi)
#pragma unroll
    for (int ni = 0; ni < 4; ++ni)
#pragma unroll
    for (int r = 0; r < 4; ++r) {
        const size_t idx =
            (size_t)(mBase + wm + 16 * mi + 4 * quad + r) * D_ +
            (nBase + wn + 16 * ni + l15);
        if (f32out) ((float*)Y)[idx] = acc[mi][ni][r];
        else        ((short*)Y)[idx] = f_to_bf16(acc[mi][ni][r]);
    }
}

// ---------------------------------------------------------------------------
// Flash attention, causal -- round-4 occupancy structure + round-7 2-q-tile
// LDS-traffic halving.
// Strips of 128 queries; wave owns rows {16w} and {64+16w} of the strip, so
// kf/vf LDS fragments are read ONCE per round and reused for TWO QK/PV
// tile-sets (32 MFMA/round/wave). Block handles strip pair {p, 15-p}
// sequentially -> exactly 34 rounds/block, perfectly balanced.
// Grid (H, 8, B) = 512 blocks; 25.6 KB LDS + launch_bounds(256,4) -> ALL
// blocks co-resident (4/CU), serial 2-barrier stage hidden by cross-block
// TLP (round 4's verified mechanism).
// Round kt of strip st: kt<2st: A,B full | kt==2st: A diag, B full |
//                       kt==2st+1 (last): A skip, B diag.
// LDS: Kt 8KB + Vt 8KB + Pl 9.2KB = 25.6KB.
// ---------------------------------------------------------------------------
template<bool DIAG>
static __device__ __forceinline__ void sm_pv(
    const floatx4* s, floatx4& lsum, floatx4* o,
    const short8 (&vf)[4][2], short* PlW,
    int l15, int quad, int q0, int kv0)
{
#pragma unroll
    for (int r = 0; r < 4; ++r) {
        float p[4];
#pragma unroll
        for (int g = 0; g < 4; ++g) {
            float t = s[g][r];
            if (DIAG) {
                const int kg = kv0 + 4 * l15 + g;
                const int qg = q0 + 4 * quad + r;
                t = (kg <= qg) ? t : -INFINITY;
            }
            p[g] = __builtin_amdgcn_exp2f(t);
        }
        lsum[r] += (p[0] + p[1]) + (p[2] + p[3]);
        uint2 pk;
        pk.x = __builtin_amdgcn_perm(
            __float_as_uint(p[1]) + 0x8000u,
            __float_as_uint(p[0]) + 0x8000u, 0x07060302u);
        pk.y = __builtin_amdgcn_perm(
            __float_as_uint(p[3]) + 0x8000u,
            __float_as_uint(p[2]) + 0x8000u, 0x07060302u);
        *(uint2*)&PlW[(4 * quad + r) * 72 + 4 * l15] = pk;
    }
    const short8 pf0 = *(const short8*)&PlW[l15 * 72 + quad * 8];
    const short8 pf1 = *(const short8*)&PlW[l15 * 72 + 32 + quad * 8];
#pragma unroll
    for (int nb = 0; nb < 4; ++nb) {
        o[nb] = MFMA16(pf0, vf[nb][0], o[nb]);
        o[nb] = MFMA16(pf1, vf[nb][1], o[nb]);
    }
}

__global__ __launch_bounds__(256, 4) void attn_kernel(
    const short* __restrict__ Q, const short* __restrict__ K,
    const short* __restrict__ VT, short* __restrict__ CTX)
{
    __shared__ __align__(16) short Kt[64 * 64];       // 8 KB
    __shared__ __align__(16) short Vt[64 * 64];       // 8 KB
    __shared__ __align__(16) short Pl[4][16 * 72];    // 9.2 KB (per-wave P)

    const int h    = blockIdx.x;
    const int pair = blockIdx.y;
    const int b    = blockIdx.z;
    const int tid  = threadIdx.x;
    const int wave = tid >> 6;
    const int lane = tid & 63;
    const int quad = lane >> 4;
    const int l15  = lane & 15;

    const size_t base   = (size_t)b * S_ * D_ + (size_t)h * HD_;
    const size_t vtbase = (size_t)(b * H_ + h) * HD_ * S_;

    // staging: thread covers 16B; 8 threads/row; swizzled source column,
    // permuted K key row (keyA/keyB) so kf[g] col=l15 maps to key 4*l15+g.
    const int rowS   = tid >> 3;
    const int colSwz = (((tid & 7) - rowS) & 7) * 8;
    const int keyA = (rowS & 15) * 4 + (rowS >> 4);
    const int keyB = ((rowS + 32) & 15) * 4 + ((rowS + 32) >> 4);

    // read-side physical blocks
    const int ph0 = ((quad + l15) & 7) * 8;
    const int ph1 = ((quad + 4 + l15) & 7) * 8;

    // fixed global staging pointers (per-round offset added in-loop)
    const short* kstA = K + base + (size_t)keyA * D_ + colSwz;
    const short* kstB = K + base + (size_t)keyB * D_ + colSwz;
    const short* vstA = VT + vtbase + (size_t)rowS * S_ + colSwz;
    const short* vstB = VT + vtbase + (size_t)(rowS + 32) * S_ + colSwz;

    const int strips[2] = { pair, 15 - pair };

    for (int sp = 0; sp < 2; ++sp) {
        const int st  = strips[sp];
        const int qs  = st * 128;
        const int q0A = qs + 16 * wave;        // tile A rows (lower half)
        const int q0B = qs + 64 + 16 * wave;   // tile B rows (upper half)

        short8 qfA[2], qfB[2];
        {
            const short* qa = Q + base + (size_t)(q0A + l15) * D_ + quad * 8;
            qfA[0] = *(const short8*)(qa);
            qfA[1] = *(const short8*)(qa + 32);
            const short* qb = Q + base + (size_t)(q0B + l15) * D_ + quad * 8;
            qfB[0] = *(const short8*)(qb);
            qfB[1] = *(const short8*)(qb + 32);
        }

        floatx4 oA[4] = {}, oB[4] = {};
        floatx4 lsumA = {}, lsumB = {};

        const int last = 2 * st + 1;

        for (int kt = 0; kt <= last; ++kt) {
            const int kv0 = kt * 64;

            __syncthreads();   // previous round's LDS reads done before overwrite
            {
                const size_t ko = (size_t)kv0 * D_;
                gl_lds16(kstA + ko, &Kt[tid * 8]);
                gl_lds16(kstB + ko, &Kt[2048 + tid * 8]);
                gl_lds16(vstA + kv0, &Vt[tid * 8]);
                gl_lds16(vstB + kv0, &Vt[2048 + tid * 8]);
            }
            __syncthreads();   // drains vmcnt; tiles visible to all waves

            // K fragments: group g = keys 4*l15+g (read ONCE, used by A and B)
            short8 kf[4][2];
#pragma unroll
            for (int g = 0; g < 4; ++g) {
                kf[g][0] = *(const short8*)&Kt[(16 * g + l15) * 64 + ph0];
                kf[g][1] = *(const short8*)&Kt[(16 * g + l15) * 64 + ph1];
            }

            const bool doA = (kt < last);   // tile A fully masked on last round

            floatx4 sA[4] = {}, sB[4] = {};
            if (doA) {
#pragma unroll
                for (int g = 0; g < 4; ++g) {
                    sA[g] = MFMA16(qfA[0], kf[g][0], sA[g]);
                    sA[g] = MFMA16(qfA[1], kf[g][1], sA[g]);
                }
            }
#pragma unroll
            for (int g = 0; g < 4; ++g) {
                sB[g] = MFMA16(qfB[0], kf[g][0], sB[g]);
                sB[g] = MFMA16(qfB[1], kf[g][1], sB[g]);
            }

            // V fragments (read ONCE, used by A and B)
            short8 vf[4][2];
#pragma unroll
            for (int nb = 0; nb < 4; ++nb) {
                vf[nb][0] = *(const short8*)&Vt[(nb * 16 + l15) * 64 + ph0];
                vf[nb][1] = *(const short8*)&Vt[(nb * 16 + l15) * 64 + ph1];
            }

            if (doA) {
                if (kt == 2 * st)
                    sm_pv<true >(sA, lsumA, oA, vf, Pl[wave], l15, quad, q0A, kv0);
                else
                    sm_pv<false>(sA, lsumA, oA, vf, Pl[wave], l15, quad, q0A, kv0);
            }
            if (kt == last)
                sm_pv<true >(sB, lsumB, oB, vf, Pl[wave], l15, quad, q0B, kv0);
            else
                sm_pv<false>(sB, lsumB, oB, vf, Pl[wave], l15, quad, q0B, kv0);
        }

        // epilogue: reduce row sums across the 16 lanes of each quad, normalize
#pragma unroll
        for (int r = 0; r < 4; ++r) {
            float la = lsumA[r];
            la += __shfl_xor(la, 1);
            la += __shfl_xor(la, 2);
            la += __shfl_xor(la, 4);
            la += __shfl_xor(la, 8);
            const float invA = 1.0f / la;
            const int rowA = q0A + 4 * quad + r;
#pragma unroll
            for (int nb = 0; nb < 4; ++nb)
                CTX[base + (size_t)rowA * D_ + nb * 16 + l15] = f_to_bf16(oA[nb][r] * invA);

            float lb = lsumB[r];
            lb += __shfl_xor(lb, 1);
            lb += __shfl_xor(lb, 2);
            lb += __shfl_xor(lb, 4);
            lb += __shfl_xor(lb, 8);
            const float invB = 1.0f / lb;
            const int rowB = q0B + 4 * quad + r;
#pragma unroll
            for (int nb = 0; nb < 4; ++nb)
                CTX[base + (size_t)rowB * D_ + nb * 16 + l15] = f_to_bf16(oB[nb][r] * invB);
        }
    }
}

// ---------------------------------------------------------------------------
extern "C" void kernel_launch(void* const* d_in, const int* in_sizes, int n_in,
                              void* d_out, int out_size, void* d_ws, size_t ws_size,
                              hipStream_t stream) {
    (void)in_sizes; (void)n_in; (void)out_size; (void)ws_size;

    const unsigned int* xraw = (const unsigned int*)d_in[0];
    const void* Wq = d_in[1];
    const void* Wk = d_in[2];
    const void* Wv = d_in[3];
    const void* Wo = d_in[4];

    const size_t NE = (size_t)B_ * S_ * D_;   // 8388608
    const size_t NW = (size_t)D_ * D_;        // 1048576

    // ws layout: [xb: NE][wqkv: 3*NW][wob: NW][q: NE][k: NE][VT: NE]
    char* wsb = (char*)d_ws;
    short* xb   = (short*)wsb;                  wsb += NE * sizeof(short);
    short* wqkv = (short*)wsb;                  wsb += 3 * NW * sizeof(short);
    short* wob  = (short*)wsb;                  wsb += NW * sizeof(short);
    short* q    = (short*)wsb;                  wsb += NE * sizeof(short);
    short* k    = (short*)wsb;                  wsb += NE * sizeof(short);
    short* VT   = (short*)wsb;                  wsb += NE * sizeof(short);
    short* ctx  = xb;

    const int conv_blocks = (int)((NE + 4 * NW) / 8 / 256);  // 6144
    convert_all_kernel<<<conv_blocks, 256, 0, stream>>>(
        (const void*)xraw, Wq, Wk, Wv, Wo, xb, xraw);

    const dim3 qkv_grid(B_ * S_ / 256, 3 * D_ / 128, 1);  // 32 x 24 = 768 = 3 rounds
    gemm_qkv256_kernel<<<qkv_grid, 512, 0, stream>>>(xb, wqkv, q, k, VT);

    const dim3 attn_grid(H_, S_ / 256, B_);  // 16 x 8 x 4 = 512 blocks, all resident
    attn_kernel<<<attn_grid, 256, 0, stream>>>(q, k, VT, ctx);

    const dim3 gemm_grid(B_ * S_ / 256, D_ / 128, 1);  // 32 x 8 = 256 = 1 round
    gemm_xwT_kernel<<<gemm_grid, 512, 0, stream>>>(ctx, wob, d_out, xraw);
}

// Round 10
// 226.973 us; speedup vs baseline: 1.6418x; 1.6418x over previous
//
#include <hip/hip_runtime.h>
#include <hip/hip_bf16.h>

// B=4, S=2048, D=1024, H=16, HD=64.
// Input dtype detected inline (fp32 vs bf16); compute pipeline is bf16 MFMA.
#define B_  4
#define S_  2048
#define D_  1024
#define H_  16
#define HD_ 64

using short4_ = __attribute__((ext_vector_type(4))) short;
using short8  = __attribute__((ext_vector_type(8))) short;
using floatx4 = __attribute__((ext_vector_type(4))) float;

#define MFMA16(a, b, c) __builtin_amdgcn_mfma_f32_16x16x32_bf16((a), (b), (c), 0, 0, 0)

// softmax scale folded into Q at QKV-GEMM epilogue: (1/sqrt(64)) * log2(e)
#define QSCALE (0.125f * 1.4426950408889634f)

static __device__ __forceinline__ short f_to_bf16(float f) {
    __hip_bfloat16 h = __float2bfloat16(f);
    short s;
    __builtin_memcpy(&s, &h, 2);
    return s;
}

// async global->LDS, 16B per lane; LDS dst must be wave-uniform base + lane*16.
static __device__ __forceinline__ void gl_lds16(const short* g, short* l) {
    __builtin_amdgcn_global_load_lds(
        (const __attribute__((address_space(1))) void*)g,
        (__attribute__((address_space(3))) void*)l, 16, 0, 0);
}

// Inline dtype detect: lanes 0..63 read x's first 64 dwords as fp32.
static __device__ __forceinline__ bool detect_fp32(const unsigned int* __restrict__ xraw) {
    const float f = __uint_as_float(xraw[threadIdx.x & 63]);
    const bool weird = !(f == f) || fabsf(f) > 1e30f;
    return __ballot(weird) == 0ull;
}

// ---------------------------------------------------------------------------
// Merged convert: virtual concat [x | Wq | Wk | Wv | Wo] -> contiguous
// bf16 [xb | wqkv(3) | wob]. One launch.
// ---------------------------------------------------------------------------
__global__ __launch_bounds__(256) void convert_all_kernel(
    const void* __restrict__ x,  const void* __restrict__ wq,
    const void* __restrict__ wk, const void* __restrict__ wv,
    const void* __restrict__ wo, short* __restrict__ dst,
    const unsigned int* __restrict__ xraw)
{
    const bool isf32 = detect_fp32(xraw);
    const size_t NE = (size_t)B_ * S_ * D_;   // 8388608
    const size_t NW = (size_t)D_ * D_;        // 1048576 = 2^20
    const size_t i = ((size_t)blockIdx.x * 256 + threadIdx.x) * 8;

    const void* src;
    size_t off;
    if (i < NE) { src = x; off = i; }
    else {
        const size_t j = i - NE;
        const int r = (int)(j >> 20);
        src = (r == 0) ? wq : (r == 1) ? wk : (r == 2) ? wv : wo;
        off = j & (NW - 1);
    }

    if (isf32) {
        const float* s = (const float*)src + off;
        short8 o;
#pragma unroll
        for (int j2 = 0; j2 < 8; ++j2) o[j2] = f_to_bf16(s[j2]);
        *(short8*)(dst + i) = o;
    } else {
        *(short8*)(dst + i) = *(const short8*)((const short*)src + off);
    }
}

// ---------------------------------------------------------------------------
// 256x128-tile pipelined GEMM core, shared by qkv and xwT kernels.
// (verified working, rounds 4-9)
// ---------------------------------------------------------------------------
#define STAGE6(BUF, KO)                                                         \
  { const short* a0_ = gA + (KO);                                               \
    gl_lds16(a0_,            (BUF) +     0 + tid * 8);                          \
    gl_lds16(a0_ +  64 * D_, (BUF) +  4096 + tid * 8);                          \
    gl_lds16(a0_ + 128 * D_, (BUF) +  8192 + tid * 8);                          \
    gl_lds16(a0_ + 192 * D_, (BUF) + 12288 + tid * 8);                          \
    const short* b0_ = gB + (KO);                                               \
    gl_lds16(b0_,            (BUF) + 16384 + tid * 8);                          \
    gl_lds16(b0_ +  64 * D_, (BUF) + 20480 + tid * 8); }

#define READ_FRAGS(AF, BF, BUF)                                                 \
  { _Pragma("unroll")                                                           \
    for (int mi = 0; mi < 4; ++mi) {                                            \
      AF[mi][0] = *(const short8*)&(BUF)[(wm + 16*mi + l15) * 64 + ((    quad + l15) & 7) * 8]; \
      AF[mi][1] = *(const short8*)&(BUF)[(wm + 16*mi + l15) * 64 + ((4 + quad + l15) & 7) * 8]; \
    }                                                                           \
    _Pragma("unroll")                                                           \
    for (int ni = 0; ni < 4; ++ni) {                                            \
      BF[ni][0] = *(const short8*)&(BUF)[16384 + (wn + 16*ni + l15) * 64 + ((    quad + l15) & 7) * 8]; \
      BF[ni][1] = *(const short8*)&(BUF)[16384 + (wn + 16*ni + l15) * 64 + ((4 + quad + l15) & 7) * 8]; \
    } }

#define DO_MFMA(AF, BF)                                                         \
  { __builtin_amdgcn_s_setprio(1);                                              \
    _Pragma("unroll")                                                           \
    for (int mi = 0; mi < 4; ++mi)                                              \
      _Pragma("unroll")                                                         \
      for (int ni = 0; ni < 4; ++ni) {                                          \
        acc[mi][ni] = MFMA16(AF[mi][0], BF[ni][0], acc[mi][ni]);                \
        acc[mi][ni] = MFMA16(AF[mi][1], BF[ni][1], acc[mi][ni]);                \
      }                                                                         \
    __builtin_amdgcn_s_setprio(0); }

#define GEMM_BODY(CURB, NXTB, AF_U, BF_U, AF_F, BF_F, KO2, S1, S2)              \
  {                                                                             \
    asm volatile("s_waitcnt lgkmcnt(0)" ::: "memory");                          \
    __builtin_amdgcn_s_barrier();                                               \
    if (S2) STAGE6(CURB, KO2)                                                   \
    if (S2) { asm volatile("s_waitcnt vmcnt(6)" ::: "memory"); }                \
    else    { asm volatile("s_waitcnt vmcnt(0)" ::: "memory"); }                \
    __builtin_amdgcn_s_barrier();                                               \
    if (S1) READ_FRAGS(AF_F, BF_F, NXTB)                                        \
    DO_MFMA(AF_U, BF_U)                                                         \
  }

#define GEMM_PREAMBLE                                                           \
    const int tid  = threadIdx.x;                                               \
    const int wave = tid >> 6;                                                  \
    const int lane = tid & 63;                                                  \
    const int quad = lane >> 4;                                                 \
    const int l15  = lane & 15;                                                 \
    const int wm   = (wave >> 1) * 64;                                          \
    const int wn   = (wave & 1) * 64;                                           \
    const int rS   = tid >> 3;                                                  \
    const int sb8  = (((tid & 7) - rS) & 7) * 8;                                \
    short* const buf0 = Lds;                                                    \
    short* const buf1 = Lds + 24576;                                            \
    short8 afA[4][2], bfA[4][2], afB[4][2], bfB[4][2];                          \
    floatx4 acc[4][4] = {};

#define GEMM_KLOOP                                                              \
    STAGE6(buf0, 0)                                                             \
    STAGE6(buf1, 64)                                                            \
    asm volatile("s_waitcnt vmcnt(6)" ::: "memory");                            \
    __builtin_amdgcn_s_barrier();                                               \
    READ_FRAGS(afA, bfA, buf0)                                                  \
    int ko = 128;                                                               \
    for (int it = 0; it < 7; ++it) {                                            \
        GEMM_BODY(buf0, buf1, afA, bfA, afB, bfB, ko,      true, true)          \
        GEMM_BODY(buf1, buf0, afB, bfB, afA, bfA, ko + 64, true, true)          \
        ko += 128;                                                              \
    }                                                                           \
    GEMM_BODY(buf0, buf1, afA, bfA, afB, bfB, 0, true,  false)  /* t=14 */      \
    GEMM_BODY(buf1, buf0, afB, bfB, afA, bfA, 0, false, false)  /* t=15 */

// ---------------------------------------------------------------------------
// Fused QKV GEMM. W = concat(Wq,Wk,Wv) rows [3072][1024]. Grid 32 x 24 =
// 768 blocks = exactly 3 full rounds on 256 CUs (zero tail waste).
// ---------------------------------------------------------------------------
__global__ __launch_bounds__(512, 2) void gemm_qkv256_kernel(
    const short* __restrict__ X, const short* __restrict__ W,
    short* __restrict__ Yq, short* __restrict__ Yk, short* __restrict__ VT)
{
    __shared__ __align__(16) short Lds[49152];   // 96 KiB

    GEMM_PREAMBLE

    const int mBase = blockIdx.x * 256;
    const int nTot  = blockIdx.y * 128;          // 0..2943
    const int sel   = nTot >> 10;                // 0=q,1=k,2=v
    const int nBase = nTot & 1023;

    const short* gA = X + (size_t)(mBase + rS) * D_ + sb8;
    const short* gB = W + (size_t)(nTot  + rS) * D_ + sb8;

    GEMM_KLOOP

    if (sel < 2) {
        short* Y = (sel == 0) ? Yq : Yk;
        const float osc = (sel == 0) ? QSCALE : 1.0f;
#pragma unroll
        for (int mi = 0; mi < 4; ++mi)
#pragma unroll
        for (int ni = 0; ni < 4; ++ni)
#pragma unroll
        for (int r = 0; r < 4; ++r) {
            const size_t idx =
                (size_t)(mBase + wm + 16 * mi + 4 * quad + r) * D_ +
                (nBase + wn + 16 * ni + l15);
            Y[idx] = f_to_bf16(acc[mi][ni][r] * osc);
        }
    } else {
        // V^T epilogue: LDS transpose (Tb = 128 chans x 256 m, stride 264),
        // coalesced 512B-row writes to VT.
        const int bb = mBase >> 11;     // batch
        const int s0 = mBase & 2047;    // seq base
        short* Tb = Lds;
        __syncthreads();   // k-loop fully drained; LDS free
#pragma unroll
        for (int ni = 0; ni < 4; ++ni)
#pragma unroll
        for (int mi = 0; mi < 4; ++mi) {
            short4_ v4;
#pragma unroll
            for (int r = 0; r < 4; ++r) v4[r] = f_to_bf16(acc[mi][ni][r]);
            *(short4_*)&Tb[(wn + 16 * ni + l15) * 264 + wm + 16 * mi + 4 * quad] = v4;
        }
        __syncthreads();
#pragma unroll
        for (int p = 0; p < 8; ++p) {
            const int t2 = tid + p * 512;
            const int cl = t2 >> 5;           // 0..127
            const int mc = (t2 & 31) * 8;     // 0..248
            const short8 val = *(const short8*)&Tb[cl * 264 + mc];
            const int c  = nBase + cl;        // global channel
            const int hh = c >> 6, hd = c & 63;
            *(short8*)&VT[((size_t)(bb * H_ + hh) * HD_ + hd) * S_ + s0 + mc] = val;
        }
    }
}

// ---------------------------------------------------------------------------
// Wo projection: Y = ctx @ Wo^T. Grid 32 x 8 = 256 blocks = exactly 1 round.
// ---------------------------------------------------------------------------
__global__ __launch_bounds__(512, 2) void gemm_xwT_kernel(
    const short* __restrict__ X, const short* __restrict__ W,
    void* __restrict__ Y, const unsigned int* __restrict__ xraw)
{
    __shared__ __align__(16) short Lds[49152];   // 96 KiB

    const bool f32out = detect_fp32(xraw);

    GEMM_PREAMBLE

    const int mBase = blockIdx.x * 256;
    const int nBase = blockIdx.y * 128;

    const short* gA = X + (size_t)(mBase + rS) * D_ + sb8;
    const short* gB = W + (size_t)(nBase + rS) * D_ + sb8;

    GEMM_KLOOP

#pragma unroll
    for (int mi = 0; mi < 4; ++mi)
#pragma unroll
    for (int ni = 0; ni < 4; ++ni)
#pragma unroll
    for (int r = 0; r < 4; ++r) {
        const size_t idx =
            (size_t)(mBase + wm + 16 * mi + 4 * quad + r) * D_ +
            (nBase + wn + 16 * ni + l15);
        if (f32out) ((float*)Y)[idx] = acc[mi][ni][r];
        else        ((short*)Y)[idx] = f_to_bf16(acc[mi][ni][r]);
    }
}

// ---------------------------------------------------------------------------
// Flash attention, causal -- REVERTED to the round-4 verified kernel
// (62.7 us, VGPR 48, 4 blocks/CU, no spills).
// Strips of 64 queries; block handles pair {j, 31-j} sequentially ->
// exactly 33 k-rounds/block (balanced). grid = (H, 16 pairs, B): same-(b,h)
// blocks are 16 apart in linear order -> same XCD -> K/VT L2-resident.
// 1024 blocks = 4/CU (launch_bounds 256,4). Serial 2-barrier stage per round
// is hidden by cross-block TLP at 4 blocks/CU (verified rounds 4 vs 6/7).
// 64-key LDS tiles, 16B-block XOR swizzle; Q pre-scaled; no-max softmax.
// LDS: Kt 8KB + Vt 8KB + Pl 9.2KB = 25.6KB.
// ---------------------------------------------------------------------------
__global__ __launch_bounds__(256, 4) void attn_kernel(
    const short* __restrict__ Q, const short* __restrict__ K,
    const short* __restrict__ VT, short* __restrict__ CTX)
{
    __shared__ __align__(16) short Kt[64 * 64];       // 8 KB
    __shared__ __align__(16) short Vt[64 * 64];       // 8 KB
    __shared__ __align__(16) short Pl[4][16 * 72];    // 9.2 KB (per-wave P)

    const int h    = blockIdx.x;
    const int pair = blockIdx.y;
    const int b    = blockIdx.z;
    const int tid  = threadIdx.x;
    const int wave = tid >> 6;
    const int lane = tid & 63;
    const int quad = lane >> 4;
    const int l15  = lane & 15;

    const size_t base   = (size_t)b * S_ * D_ + (size_t)h * HD_;
    const size_t vtbase = (size_t)(b * H_ + h) * HD_ * S_;

    // staging: thread covers 16B; 8 threads/row; swizzled source column
    const int rowS   = tid >> 3;
    const int colSwz = (((tid & 7) - rowS) & 7) * 8;
    const int keyA = (rowS & 15) * 4 + (rowS >> 4);               // permuted key, p=0
    const int keyB = ((rowS + 32) & 15) * 4 + ((rowS + 32) >> 4); // permuted key, p=1

    // read-side physical blocks (logical block = half*4 + quad, row = ...+l15)
    const int ph0 = ((quad + l15) & 7) * 8;
    const int ph1 = ((quad + 4 + l15) & 7) * 8;

    const int strips[2] = { pair, 31 - pair };

    for (int sp = 0; sp < 2; ++sp) {
        const int st  = strips[sp];
        const int q0w = st * 64 + wave * 16;

        // Q fragment: 2 k-halves (pre-scaled by QSCALE)
        short8 qf[2];
        {
            const short* qrow = Q + base + (size_t)(q0w + l15) * D_ + quad * 8;
            qf[0] = *(const short8*)(qrow);
            qf[1] = *(const short8*)(qrow + 32);
        }

        floatx4 o[4] = {};
        floatx4 lsum = {};

        for (int kt = 0; kt <= st; ++kt) {
            const int kv0 = kt * 64;

            __syncthreads();  // previous round's LDS reads done before overwrite
            gl_lds16(K + base + (size_t)(kv0 + keyA) * D_ + colSwz, &Kt[tid * 8]);
            gl_lds16(K + base + (size_t)(kv0 + keyB) * D_ + colSwz, &Kt[2048 + tid * 8]);
            gl_lds16(VT + vtbase + (size_t)rowS * S_ + kv0 + colSwz, &Vt[tid * 8]);
            gl_lds16(VT + vtbase + (size_t)(rowS + 32) * S_ + kv0 + colSwz, &Vt[2048 + tid * 8]);
            __syncthreads();  // drains vmcnt; tiles visible to all waves

            // K fragments: group g = keys 4*l15+g
            short8 kf[4][2];
#pragma unroll
            for (int g = 0; g < 4; ++g) {
                kf[g][0] = *(const short8*)&Kt[(16 * g + l15) * 64 + ph0];
                kf[g][1] = *(const short8*)&Kt[(16 * g + l15) * 64 + ph1];
            }

            floatx4 s[4] = {};
#pragma unroll
            for (int g = 0; g < 4; ++g) {
                s[g] = MFMA16(qf[0], kf[g][0], s[g]);
                s[g] = MFMA16(qf[1], kf[g][1], s[g]);
            }

            if (kt < st) {
                // full tile: no masking
#pragma unroll
                for (int r = 0; r < 4; ++r) {
                    float p[4];
#pragma unroll
                    for (int g = 0; g < 4; ++g)
                        p[g] = __builtin_amdgcn_exp2f(s[g][r]);
                    lsum[r] += (p[0] + p[1]) + (p[2] + p[3]);
                    uint2 pk;
                    pk.x = __builtin_amdgcn_perm(
                        __float_as_uint(p[1]) + 0x8000u,
                        __float_as_uint(p[0]) + 0x8000u, 0x07060302u);
                    pk.y = __builtin_amdgcn_perm(
                        __float_as_uint(p[3]) + 0x8000u,
                        __float_as_uint(p[2]) + 0x8000u, 0x07060302u);
                    *(uint2*)&Pl[wave][(4 * quad + r) * 72 + 4 * l15] = pk;
                }
            } else {
                // diagonal tile: causal mask
#pragma unroll
                for (int r = 0; r < 4; ++r) {
                    const int qg = q0w + 4 * quad + r;
                    float p[4];
#pragma unroll
                    for (int g = 0; g < 4; ++g) {
                        const int kg = kv0 + 4 * l15 + g;
                        const float t = (kg <= qg) ? s[g][r] : -INFINITY;
                        p[g] = __builtin_amdgcn_exp2f(t);
                    }
                    lsum[r] += (p[0] + p[1]) + (p[2] + p[3]);
                    uint2 pk;
                    pk.x = __builtin_amdgcn_perm(
                        __float_as_uint(p[1]) + 0x8000u,
                        __float_as_uint(p[0]) + 0x8000u, 0x07060302u);
                    pk.y = __builtin_amdgcn_perm(
                        __float_as_uint(p[3]) + 0x8000u,
                        __float_as_uint(p[2]) + 0x8000u, 0x07060302u);
                    *(uint2*)&Pl[wave][(4 * quad + r) * 72 + 4 * l15] = pk;
                }
            }

            // V fragments + PV (per-wave P buffer; compiler inserts lgkmcnt)
            const short8 pf0 = *(const short8*)&Pl[wave][l15 * 72 + quad * 8];
            const short8 pf1 = *(const short8*)&Pl[wave][l15 * 72 + 32 + quad * 8];
#pragma unroll
            for (int nb = 0; nb < 4; ++nb) {
                const short8 vf0 = *(const short8*)&Vt[(nb * 16 + l15) * 64 + ph0];
                const short8 vf1 = *(const short8*)&Vt[(nb * 16 + l15) * 64 + ph1];
                o[nb] = MFMA16(pf0, vf0, o[nb]);
                o[nb] = MFMA16(pf1, vf1, o[nb]);
            }
        }

        // epilogue: reduce row sums across the 16 lanes of each quad, normalize
#pragma unroll
        for (int r = 0; r < 4; ++r) {
            float l = lsum[r];
            l += __shfl_xor(l, 1);
            l += __shfl_xor(l, 2);
            l += __shfl_xor(l, 4);
            l += __shfl_xor(l, 8);
            const float inv = 1.0f / l;
            const int row = q0w + 4 * quad + r;
#pragma unroll
            for (int nb = 0; nb < 4; ++nb)
                CTX[base + (size_t)row * D_ + nb * 16 + l15] = f_to_bf16(o[nb][r] * inv);
        }
    }
}

// ---------------------------------------------------------------------------
extern "C" void kernel_launch(void* const* d_in, const int* in_sizes, int n_in,
                              void* d_out, int out_size, void* d_ws, size_t ws_size,
                              hipStream_t stream) {
    (void)in_sizes; (void)n_in; (void)out_size; (void)ws_size;

    const unsigned int* xraw = (const unsigned int*)d_in[0];
    const void* Wq = d_in[1];
    const void* Wk = d_in[2];
    const void* Wv = d_in[3];
    const void* Wo = d_in[4];

    const size_t NE = (size_t)B_ * S_ * D_;   // 8388608
    const size_t NW = (size_t)D_ * D_;        // 1048576

    // ws layout: [xb: NE][wqkv: 3*NW][wob: NW][q: NE][k: NE][VT: NE]
    char* wsb = (char*)d_ws;
    short* xb   = (short*)wsb;                  wsb += NE * sizeof(short);
    short* wqkv = (short*)wsb;                  wsb += 3 * NW * sizeof(short);
    short* wob  = (short*)wsb;                  wsb += NW * sizeof(short);
    short* q    = (short*)wsb;                  wsb += NE * sizeof(short);
    short* k    = (short*)wsb;                  wsb += NE * sizeof(short);
    short* VT   = (short*)wsb;                  wsb += NE * sizeof(short);
    short* ctx  = xb;

    const int conv_blocks = (int)((NE + 4 * NW) / 8 / 256);  // 6144
    convert_all_kernel<<<conv_blocks, 256, 0, stream>>>(
        (const void*)xraw, Wq, Wk, Wv, Wo, xb, xraw);

    const dim3 qkv_grid(B_ * S_ / 256, 3 * D_ / 128, 1);  // 32 x 24 = 768 = 3 rounds
    gemm_qkv256_kernel<<<qkv_grid, 512, 0, stream>>>(xb, wqkv, q, k, VT);

    const dim3 attn_grid(H_, S_ / 128, B_);  // 16 x 16 x 4 (h-major, 64q strip pairs)
    attn_kernel<<<attn_grid, 256, 0, stream>>>(q, k, VT, ctx);

    const dim3 gemm_grid(B_ * S_ / 256, D_ / 128, 1);  // 32 x 8 = 256 = 1 round
    gemm_xwT_kernel<<<gemm_grid, 512, 0, stream>>>(ctx, wob, d_out, xraw);
}